// Round 15
// baseline (385.820 us; speedup 1.0000x reference)
//
#include <hip/hip_runtime.h>

#define CC 100000
#define DD 512

#define S_SCALE 30.0f
#define COS_M_C 0.8775825618903728f
#define SIN_M_C 0.479425538604203f
#define THRESH_C (-0.8775825618903728f)
#define MM_C 0.2397127693021015f

typedef __attribute__((ext_vector_type(8))) short short8;
typedef __attribute__((ext_vector_type(4))) float f32x4;

static __device__ __forceinline__ unsigned short f2bf(float x) {
  unsigned int u = __float_as_uint(x);
  unsigned int r = (u + 0x7fffu + ((u >> 16) & 1u)) >> 16;
  return (unsigned short)r;
}

#define FENCE() __builtin_amdgcn_sched_barrier(0)

// ---------------------------------------------------------------------------
// Kernel 1: per embedding row i: normalize, bf16, store to wsA in MFMA
// FRAGMENT order (validated r8-r14):
//   byte addr = (k>>5)*32768 + (i>>6)*4096 + ((i>>4)&3)*1024
//             + (((k>>3)&3)*16 + (i&15))*16
// ---------------------------------------------------------------------------
__global__ __launch_bounds__(64) void k1_prep(
    const float* __restrict__ emb, const float* __restrict__ kern,
    const int* __restrict__ label, unsigned short* __restrict__ wsA,
    float* __restrict__ ws_target, float* __restrict__ ws_ctm,
    float* __restrict__ ws_ft) {
  const int i = blockIdx.x;
  const int l = threadIdx.x;

  const float4* er = reinterpret_cast<const float4*>(emb + (size_t)i * DD + l * 8);
  float4 v0 = er[0], v1 = er[1];
  float e[8] = {v0.x, v0.y, v0.z, v0.w, v1.x, v1.y, v1.z, v1.w};

  float esq = 0.f;
#pragma unroll
  for (int j = 0; j < 8; ++j) esq += e[j] * e[j];
#pragma unroll
  for (int o = 32; o > 0; o >>= 1) esq += __shfl_xor(esq, o);
  const float inv = rsqrtf(esq);

  const int c = label[i];
  float dot = 0.f, wsq = 0.f;
#pragma unroll
  for (int j = 0; j < 8; ++j) {
    float w = kern[(size_t)(l * 8 + j) * CC + c];
    dot += e[j] * w;
    wsq += w * w;
  }
#pragma unroll
  for (int o = 32; o > 0; o >>= 1) {
    dot += __shfl_xor(dot, o);
    wsq += __shfl_xor(wsq, o);
  }

  unsigned int pk[4];
#pragma unroll
  for (int j = 0; j < 4; ++j) {
    unsigned int lo = f2bf(e[2 * j] * inv);
    unsigned int hi = f2bf(e[2 * j + 1] * inv);
    pk[j] = lo | (hi << 16);
  }
  const int off = (l >> 2) * 32768 + (i >> 6) * 4096 + (((i >> 4) & 3)) * 1024 +
                  ((l & 3) * 16 + (i & 15)) * 16;
  uint4 v; v.x = pk[0]; v.y = pk[1]; v.z = pk[2]; v.w = pk[3];
  *reinterpret_cast<uint4*>(reinterpret_cast<char*>(wsA) + off) = v;

  if (l == 0) {
    float t = dot * rsqrtf(fmaxf(esq * wsq, 1e-30f));
    t = fminf(fmaxf(t, -1.f), 1.f);
    float st = sqrtf(fmaxf(0.f, 1.f - t * t));
    float ctm = t * COS_M_C - st * SIN_M_C;
    ws_target[i] = t;
    ws_ctm[i] = ctm;
    ws_ft[i] = (t > THRESH_C) ? ctm : (t - MM_C);
  }
}

// ---------------------------------------------------------------------------
// Kernel 2: deterministic reduction of 512 target logits -> t_new
// ---------------------------------------------------------------------------
__global__ __launch_bounds__(64) void k2_tnew(const float* __restrict__ ws_target,
                                              const float* __restrict__ t_in,
                                              float* __restrict__ ws_tnew) {
  const int l = threadIdx.x;
  float s = 0.f;
#pragma unroll
  for (int j = 0; j < 8; ++j) s += ws_target[l * 8 + j];
#pragma unroll
  for (int o = 32; o > 0; o >>= 1) s += __shfl_xor(s, o);
  if (l == 0) ws_tnew[0] = 0.01f * (s * (1.0f / 512.0f)) + 0.99f * t_in[0];
}

// ---------------------------------------------------------------------------
// Kernel 3: 512x64 tile GEMM + epilogue, BK=64 -> EIGHT iterations.
// Halves the per-iteration fixed cost (barrier skew + waitcnt chains) that
// the r4-r13 accounting identified as the dominant unexplained term:
// 32 MFMA per barrier instead of 16.
//  - A: direct global->VGPR fragment loads (fragment-order wsA, L2-hot).
//    Both k-halves (af[8]) issued at iter top -> >=400cy cover.
//  - B: LDS double-buffer 2x8KB, layout [col][k] (col stride 128B) with
//    chunk-XOR swizzle c^(col&7) -> <=2-way on both write and read.
//    Wave wv stages k=g*64+8wv..+7 of its column (8 floats, 8 loads).
//  - ONE barrier per iteration; write buffer != read buffer both ways.
// Queue (traced): entry [B(g+1):8]; af[8] -> [B:8,af:8]; vmcnt(8) retires
// B; BWRITE8(g+1) (g<7); BLOAD8(g+2) (g<6) -> [af:8,B':8]; ds_reads;
// vmcnt(g<6?8:0) retires af (B' flies over barrier); 32 MFMA in 2+2
// chunks; barrier. Register audit: 64 AGPR acc + 32 af + 8 p + 8 bfr
// + ~12 addr = 124 <= 128.
// ---------------------------------------------------------------------------
__global__ __launch_bounds__(512, 4) void k3_gemm(
    const float* __restrict__ kern, const unsigned short* __restrict__ wsA,
    const int* __restrict__ label, const float* __restrict__ ws_ctm,
    const float* __restrict__ ws_ft, const float* __restrict__ ws_tnew,
    float* __restrict__ out) {
  __shared__ __align__(16) char smem[16384 + 8704];  // B 2x8KB + est 8x1088B
  __shared__ float colsq[64];

  const int t = threadIdx.x;
  const int l = t & 63;
  const int wv = t >> 6;  // 0..7
  const int lr = l & 15;
  const int lg = l >> 4;
  const int n0 = blockIdx.x * 64;

  if (t < 64) colsq[t] = 0.f;

  const int bn = l;
  const int gcol = n0 + bn;
  const bool colok = gcol < CC;
  const float* bcol = kern + gcol;

  float sumsq = 0.f;

  f32x4 acc[4][4];
#pragma unroll
  for (int a = 0; a < 4; ++a)
#pragma unroll
    for (int b = 0; b < 4; ++b) acc[a][b] = (f32x4){0.f, 0.f, 0.f, 0.f};

  char* Bb = smem;
  const char* pA = reinterpret_cast<const char*>(wsA) + wv * 4096 + l * 16;
  // write: wave wv supplies 16B chunk wv of col bn, swizzled ^(bn&7)
  const int wb = bn * 128 + ((wv ^ (bn & 7)) << 4);

#define BLOAD8(G, r0, r1, r2, r3, r4, r5, r6, r7)                        \
  {                                                                      \
    if (colok) {                                                         \
      const float* q_ = bcol + (size_t)((G) * 64 + wv * 8) * CC;         \
      r0 = q_[0];              r1 = q_[(size_t)CC];                      \
      r2 = q_[(size_t)2 * CC]; r3 = q_[(size_t)3 * CC];                  \
      r4 = q_[(size_t)4 * CC]; r5 = q_[(size_t)5 * CC];                  \
      r6 = q_[(size_t)6 * CC]; r7 = q_[(size_t)7 * CC];                  \
    } else {                                                             \
      r0 = r1 = r2 = r3 = r4 = r5 = r6 = r7 = 0.f;                       \
    }                                                                    \
  }

#define BWRITE8(G, r0, r1, r2, r3, r4, r5, r6, r7)                       \
  {                                                                      \
    sumsq += r0 * r0 + r1 * r1 + r2 * r2 + r3 * r3 + r4 * r4 + r5 * r5 + \
             r6 * r6 + r7 * r7;                                          \
    uint4 pk_;                                                           \
    pk_.x = (unsigned int)f2bf(r0) | ((unsigned int)f2bf(r1) << 16);     \
    pk_.y = (unsigned int)f2bf(r2) | ((unsigned int)f2bf(r3) << 16);     \
    pk_.z = (unsigned int)f2bf(r4) | ((unsigned int)f2bf(r5) << 16);     \
    pk_.w = (unsigned int)f2bf(r6) | ((unsigned int)f2bf(r7) << 16);     \
    *reinterpret_cast<uint4*>(Bb + ((G)&1) * 8192 + wb) = pk_;           \
  }

  // b-frag read address: col n, k-half h, k-slice lg -> chunk (h*4+lg)^(n&7)
#define BREAD(NF, H)                                                      \
  (*reinterpret_cast<const short8*>(                                      \
      Bb + cur * 8192 + (NF * 16 + lr) * 128 +                            \
      ((((H) * 4 + lg) ^ ((NF * 16 + lr) & 7)) << 4)))

  // ---- prologue ----
  float q0, q1, q2, q3, q4, q5, q6, q7;  // B(0)
  float p0, p1, p2, p3, p4, p5, p6, p7;  // B(g+1), loop-carried
  BLOAD8(0, q0, q1, q2, q3, q4, q5, q6, q7);
  FENCE();
  BLOAD8(1, p0, p1, p2, p3, p4, p5, p6, p7);
  FENCE();
  // queue: [B0:8, B1:8]
  asm volatile("s_waitcnt vmcnt(8)" ::: "memory");  // B0 landed
  BWRITE8(0, q0, q1, q2, q3, q4, q5, q6, q7);
  asm volatile("s_waitcnt lgkmcnt(0)" ::: "memory");
  FENCE();
  __builtin_amdgcn_s_barrier();
  FENCE();
  // enter loop: queue = [B1:8]

  for (int g = 0; g < 8; ++g) {
    const int cur = g & 1;
    // 1. both k-halves of A for this iteration (8 frags, L2-hot)
    short8 af[8];
#pragma unroll
    for (int mf = 0; mf < 4; ++mf) {
      af[mf] = *reinterpret_cast<const short8*>(pA + g * 65536 + mf * 1024);
      af[4 + mf] =
          *reinterpret_cast<const short8*>(pA + g * 65536 + 32768 + mf * 1024);
    }
    FENCE();
    // 2-4. retire B(g+1) regs (iter-old), commit, issue B(g+2)
    asm volatile("s_waitcnt vmcnt(8)" ::: "memory");
    if (g < 7) {
      BWRITE8(g + 1, p0, p1, p2, p3, p4, p5, p6, p7);
    }
    if (g < 6) {
      BLOAD8(g + 2, p0, p1, p2, p3, p4, p5, p6, p7);
    }
    FENCE();
    // 5. first b-frag pair, then retire af (B(g+2) flies over the barrier)
    short8 b0 = BREAD(0, 0), b1 = BREAD(1, 0);
    if (g < 6) {
      asm volatile("s_waitcnt vmcnt(8)" ::: "memory");
    } else {
      asm volatile("s_waitcnt vmcnt(0)" ::: "memory");
    }
    asm volatile("s_waitcnt lgkmcnt(0)" ::: "memory");
    FENCE();
    // 6. MFMA: 32 in four 2-nf chunks (bfr stays at 2 live frags)
    __builtin_amdgcn_s_setprio(1);
#pragma unroll
    for (int mf = 0; mf < 4; ++mf) {
      acc[mf][0] = __builtin_amdgcn_mfma_f32_16x16x32_bf16(af[mf], b0,
                                                           acc[mf][0], 0, 0, 0);
      acc[mf][1] = __builtin_amdgcn_mfma_f32_16x16x32_bf16(af[mf], b1,
                                                           acc[mf][1], 0, 0, 0);
    }
    b0 = BREAD(2, 0); b1 = BREAD(3, 0);
    asm volatile("s_waitcnt lgkmcnt(0)" ::: "memory");
    FENCE();
#pragma unroll
    for (int mf = 0; mf < 4; ++mf) {
      acc[mf][2] = __builtin_amdgcn_mfma_f32_16x16x32_bf16(af[mf], b0,
                                                           acc[mf][2], 0, 0, 0);
      acc[mf][3] = __builtin_amdgcn_mfma_f32_16x16x32_bf16(af[mf], b1,
                                                           acc[mf][3], 0, 0, 0);
    }
    b0 = BREAD(0, 1); b1 = BREAD(1, 1);
    asm volatile("s_waitcnt lgkmcnt(0)" ::: "memory");
    FENCE();
#pragma unroll
    for (int mf = 0; mf < 4; ++mf) {
      acc[mf][0] = __builtin_amdgcn_mfma_f32_16x16x32_bf16(af[4 + mf], b0,
                                                           acc[mf][0], 0, 0, 0);
      acc[mf][1] = __builtin_amdgcn_mfma_f32_16x16x32_bf16(af[4 + mf], b1,
                                                           acc[mf][1], 0, 0, 0);
    }
    b0 = BREAD(2, 1); b1 = BREAD(3, 1);
    asm volatile("s_waitcnt lgkmcnt(0)" ::: "memory");
    FENCE();
#pragma unroll
    for (int mf = 0; mf < 4; ++mf) {
      acc[mf][2] = __builtin_amdgcn_mfma_f32_16x16x32_bf16(af[4 + mf], b0,
                                                           acc[mf][2], 0, 0, 0);
      acc[mf][3] = __builtin_amdgcn_mfma_f32_16x16x32_bf16(af[4 + mf], b1,
                                                           acc[mf][3], 0, 0, 0);
    }
    __builtin_amdgcn_s_setprio(0);
    FENCE();
    // 7. single barrier per iteration
    __builtin_amdgcn_s_barrier();
    FENCE();
  }

  // ---- column-norm reduce (8 waves, disjoint k-slices) ----
  atomicAdd(&colsq[bn], sumsq);
  asm volatile("s_waitcnt lgkmcnt(0)" ::: "memory");
  FENCE();
  __builtin_amdgcn_s_barrier();
  FENCE();

  const float tnew = ws_tnew[0];
  float invn[4];
#pragma unroll
  for (int nf = 0; nf < 4; ++nf)
    invn[nf] = rsqrtf(fmaxf(colsq[nf * 16 + lr], 1e-30f));

  // ---- epilogue: 4-row phased transpose through wave-private LDS ----
  float* est = reinterpret_cast<float*>(smem + 16384) + (size_t)wv * 272;
  const int c4 = n0 + lr * 4;
#pragma unroll
  for (int mf = 0; mf < 4; ++mf) {
#pragma unroll
    for (int p = 0; p < 4; ++p) {
      asm volatile("s_waitcnt lgkmcnt(0)" ::: "memory");  // WAR vs prev phase
      FENCE();
      if (lg == p) {
#pragma unroll
        for (int r = 0; r < 4; ++r)
#pragma unroll
          for (int nf = 0; nf < 4; ++nf)
            est[r * 68 + nf * 16 + lr] = acc[mf][nf][r] * invn[nf];
      }
      asm volatile("s_waitcnt lgkmcnt(0)" ::: "memory");  // RAW
      FENCE();
      const int m = wv * 64 + mf * 16 + p * 4 + lg;
      const float ctm = ws_ctm[m];
      const float ft = ws_ft[m];
      const int lab = label[m];
      float4 vv = *reinterpret_cast<const float4*>(&est[lg * 68 + lr * 4]);
      if (c4 < CC) {
        float ov[4] = {vv.x, vv.y, vv.z, vv.w};
#pragma unroll
        for (int jj = 0; jj < 4; ++jj) {
          float cosv = fminf(fmaxf(ov[jj], -1.f), 1.f);
          float val = (cosv > ctm) ? cosv * (tnew + cosv) : cosv;
          if (c4 + jj == lab) val = ft;
          ov[jj] = val * S_SCALE;
        }
        float4 st4;
        st4.x = ov[0]; st4.y = ov[1]; st4.z = ov[2]; st4.w = ov[3];
        *reinterpret_cast<float4*>(out + (size_t)m * CC + c4) = st4;
      }
    }
  }
#undef BLOAD8
#undef BWRITE8
#undef BREAD
}

// ---------------------------------------------------------------------------
extern "C" void kernel_launch(void* const* d_in, const int* in_sizes, int n_in,
                              void* d_out, int out_size, void* d_ws,
                              size_t ws_size, hipStream_t stream) {
  (void)in_sizes; (void)n_in; (void)out_size; (void)ws_size;
  const float* emb = (const float*)d_in[0];
  const float* kern = (const float*)d_in[1];
  const int* label = (const int*)d_in[2];
  const float* t_in = (const float*)d_in[3];
  float* out = (float*)d_out;

  char* ws = (char*)d_ws;
  unsigned short* wsA = (unsigned short*)ws;
  float* ws_target = (float*)(ws + 524288);
  float* ws_ctm = (float*)(ws + 526336);
  float* ws_ft = (float*)(ws + 528384);
  float* ws_tnew = (float*)(ws + 530432);

  k1_prep<<<512, 64, 0, stream>>>(emb, kern, label, wsA, ws_target, ws_ctm, ws_ft);
  k2_tnew<<<1, 64, 0, stream>>>(ws_target, t_in, ws_tnew);
  k3_gemm<<<(CC + 63) / 64, 512, 0, stream>>>(kern, wsA, label, ws_ctm, ws_ft,
                                              ws_tnew, out);
}